// Round 14
// baseline (104.817 us; speedup 1.0000x reference)
//
#include <hip/hip_runtime.h>
#include <stdint.h>

// Problem constants
#define T_DIM 2048
#define B_DIM 32
#define DIN   512
#define DOUT  512
#define M_DIM (T_DIM * B_DIM)   // 65536
#define COLS  (B_DIM * DIN)     // 16384
#define COLS4 (COLS / 4)        // 4096

#define ALPHA_F 0.36787944117144233f  // exp(-1)
#define INV_1MA 1.5819767068693265f   // 1/(1-alpha)

// LDS-staged filter tiling (r13, proven): 32 out-t x 32 float4, 8-t halo.
#define FT_T    32
#define FT_HALO 8
#define FT_ROWS (FT_T + FT_HALO)   // 40 staged rows
#define FT_C4   32
#define FT_TT   (T_DIM / FT_T)     // 64
#define FT_CT   (COLS4 / FT_C4)    // 128

// Deep-pipelined GEMM: 256x256 tile, BK=32, 4-buffer counted-vmcnt pipeline.
#define GBK  32
#define NKT  (DIN / GBK)   // 16

// Fallback-path chunking (fp32 path, only if ws < 64.5 MB)
#define FCHUNKS  32
#define FCHUNK_T 64
#define FHALO    16

typedef float  floatx4 __attribute__((ext_vector_type(4)));
typedef __bf16 bf16x8  __attribute__((ext_vector_type(8)));

// pack two fp32 -> two bf16 (RNE) in one u32
__device__ __forceinline__ uint32_t pk2(float a, float b) {
  uint32_t ua = __float_as_uint(a); ua += 0x7fffu + ((ua >> 16) & 1u);
  uint32_t ub = __float_as_uint(b); ub += 0x7fffu + ((ub >> 16) & 1u);
  return (ua >> 16) | (ub & 0xffff0000u);
}

__device__ __forceinline__ void gload_lds16(const void* g, void* lds) {
  __builtin_amdgcn_global_load_lds(
      (const __attribute__((address_space(1))) void*)g,
      (__attribute__((address_space(3))) void*)lds,
      16, 0, 0);
}

__device__ __forceinline__ void fma4(float4& c, const float4& v) {
  c.x = fmaf(ALPHA_F, c.x, v.x);
  c.y = fmaf(ALPHA_F, c.y, v.y);
  c.z = fmaf(ALPHA_F, c.z, v.z);
  c.w = fmaf(ALPHA_F, c.w, v.w);
}

// counted vmcnt wait (literal immediates) + scheduler fence (rule #18)
__device__ __forceinline__ void waitcnt_vm(int n) {
  switch (n) {
    case 12: asm volatile("s_waitcnt vmcnt(12)" ::: "memory"); break;
    case 8:  asm volatile("s_waitcnt vmcnt(8)"  ::: "memory"); break;
    case 4:  asm volatile("s_waitcnt vmcnt(4)"  ::: "memory"); break;
    default: asm volatile("s_waitcnt vmcnt(0)"  ::: "memory"); break;
  }
  __builtin_amdgcn_sched_barrier(0);
}

// ---------------------------------------------------------------------------
// Kernel 1: LDS-staged exponential filter (fp32 X -> bf16 XF) + W conversion.
// (unchanged from round 13 — at its mixed-stream plateau ~46 us)
// ---------------------------------------------------------------------------
__global__ void filter_x_kernel(const float* __restrict__ X,
                                uint16_t* __restrict__ XF,
                                const float* __restrict__ W,
                                uint16_t* __restrict__ WB)
{
  __shared__ __align__(16) float4 L4[FT_ROWS * FT_C4];   // 20 KB

  if (blockIdx.y == FT_TT) {
    const int base = (blockIdx.x * 256 + threadIdx.x) * 8;
    const float4* W4 = (const float4*)W;
    float4 w0 = W4[base / 4];
    float4 w1 = W4[base / 4 + 1];
    uint4 p;
    p.x = pk2(w0.x, w0.y); p.y = pk2(w0.z, w0.w);
    p.z = pk2(w1.x, w1.y); p.w = pk2(w1.z, w1.w);
    *(uint4*)&WB[base] = p;
    return;
  }

  const int ct = blockIdx.x;
  const int tt = blockIdx.y;
  const int tid  = threadIdx.x;
  const int lane = tid & 63;
  const int w    = tid >> 6;
  const int t0   = tt * FT_T;
  const size_t gc4 = (size_t)ct * FT_C4;

  const int lrow = lane >> 5;
  const int lcol = lane & 31;

  if (tt == 0) {
    const float4 z = {0.0f, 0.0f, 0.0f, 0.0f};
    L4[tid] = z;
#pragma unroll
    for (int i = 0; i < 4; ++i) {
      const int row = 8 + (w * 4 + i) * 2;
      gload_lds16(X + ((size_t)(t0 + row - 8 + lrow) * COLS4 + gc4 + lcol) * 4,
                  &L4[row * FT_C4]);
    }
  } else {
#pragma unroll
    for (int i = 0; i < 5; ++i) {
      const int row = (w * 5 + i) * 2;
      gload_lds16(X + ((size_t)(t0 - 8 + row + lrow) * COLS4 + gc4 + lcol) * 4,
                  &L4[row * FT_C4]);
    }
  }
  __syncthreads();

  const int tg  = tid >> 5;
  const int col = tid & 31;
  float4 carry = {0.0f, 0.0f, 0.0f, 0.0f};
#pragma unroll
  for (int j = 0; j < 12; ++j) {
    float4 v = L4[(tg * 4 + j) * FT_C4 + col];
    fma4(carry, v);
    if (j >= 8) {
      const int o = tg * 4 + j - 8;
      uint2 p;
      p.x = pk2(carry.x, carry.y);
      p.y = pk2(carry.z, carry.w);
      *(uint2*)&XF[((size_t)(t0 + o) * COLS4 + gc4 + col) * 4] = p;
    }
  }
}

// ---------------------------------------------------------------------------
// Kernel 2: deep-pipelined bf16 GEMM, 256x256 tile, BK=32, 4 LDS buffers.
// 512 thr / 8 waves (2m x 4n); per-wave output 128x64 (8x4 16x16 frags).
// Counted-vmcnt pipeline: STAGE(kt+3) -> vmcnt(12) -> s_barrier -> ds_read
// (swizzle slot = q ^ ((row>>2)&3), bank-verified conflict-free) -> 32 MFMA
// -> lgkmcnt(0) -> s_barrier. Loads NEVER drain to 0 inside the loop (the
// __syncthreads vmcnt(0) drain is what caps the m97 structure at ~905 TF).
// Buffer hazard: STAGE(kt+3) writes buf[(kt-1)&3], whose reads drained
// before the previous end-barrier.
// ---------------------------------------------------------------------------
__launch_bounds__(512, 2)
__global__ void gemm_bf16_deep(const uint16_t* __restrict__ XF,
                               const uint16_t* __restrict__ WB,
                               const float* __restrict__ bias,
                               float* __restrict__ Y)
{
  __shared__ __align__(16) uint16_t As[4][256 * GBK];   // 4 x 16 KB
  __shared__ __align__(16) uint16_t Bs[4][256 * GBK];   // 4 x 16 KB

  // XCD chunked swizzle: 512 blocks = 8 XCDs x 64
  const int bid = blockIdx.x;
  const int lg  = (bid & 7) * 64 + (bid >> 3);
  const int n0  = (lg & 1) * 256;
  const int m0  = (lg >> 1) * 256;

  const int tid  = threadIdx.x;      // 0..511
  const int lane = tid & 63;
  const int w    = tid >> 6;         // 0..7
  const int wm   = w >> 2;           // 0..1
  const int wn   = w & 3;            // 0..3
  const int r    = lane & 15;
  const int q    = lane >> 4;        // 0..3

  // staging: instr i (0,1): per-lane chunk c = tid + i*512 (16B chunks);
  // row = c>>2 (0..255), slot = c&3; logical k-chunk lc = slot ^ ((row>>2)&3)
  // LDS dest wave-uniform base: (w*64 + i*512) chunks; HW adds lane*16.

#define STAGE(KT)                                                            \
  {                                                                          \
    const int b_ = (KT) & 3;                                                 \
    _Pragma("unroll")                                                        \
    for (int i = 0; i < 2; ++i) {                                            \
      const int c   = tid + i * 512;                                         \
      const int row = c >> 2;                                                \
      const int lc  = (c & 3) ^ ((row >> 2) & 3);                            \
      uint16_t* ldsA = (uint16_t*)&As[b_][(w * 64 + i * 512) * 8];           \
      uint16_t* ldsB = (uint16_t*)&Bs[b_][(w * 64 + i * 512) * 8];           \
      gload_lds16(XF + (size_t)(m0 + row) * DIN + (KT) * GBK + lc * 8, ldsA);\
      gload_lds16(WB + (size_t)(n0 + row) * DIN + (KT) * GBK + lc * 8, ldsB);\
    }                                                                        \
  }

  floatx4 acc[8][4];
#pragma unroll
  for (int i = 0; i < 8; ++i)
#pragma unroll
    for (int j = 0; j < 4; ++j) {
      floatx4 z = {0.0f, 0.0f, 0.0f, 0.0f};
      acc[i][j] = z;
    }

  // prologue: fill 3 buffers (12 loads/thread in flight)
  STAGE(0);
  STAGE(1);
  STAGE(2);

  for (int kt = 0; kt < NKT; ++kt) {
    if (kt + 3 < NKT) STAGE(kt + 3);

    // wait for kt's 4 loads: keep 4 * (tiles still in flight) outstanding
    waitcnt_vm(kt < NKT - 3 ? 12 : 4 * (NKT - 1 - kt));
    __builtin_amdgcn_s_barrier();
    __builtin_amdgcn_sched_barrier(0);

    const int b_ = kt & 3;
    bf16x8 af[8], bfr[4];
#pragma unroll
    for (int mi = 0; mi < 8; ++mi) {
      const int row  = wm * 128 + mi * 16 + r;
      const int slot = q ^ ((row >> 2) & 3);
      af[mi] = *(const bf16x8*)&As[b_][row * GBK + slot * 8];
    }
#pragma unroll
    for (int ni = 0; ni < 4; ++ni) {
      const int row  = wn * 64 + ni * 16 + r;
      const int slot = q ^ ((row >> 2) & 3);
      bfr[ni] = *(const bf16x8*)&Bs[b_][row * GBK + slot * 8];
    }
#pragma unroll
    for (int mi = 0; mi < 8; ++mi)
#pragma unroll
      for (int ni = 0; ni < 4; ++ni)
        acc[mi][ni] = __builtin_amdgcn_mfma_f32_16x16x32_bf16(
            af[mi], bfr[ni], acc[mi][ni], 0, 0, 0);

    asm volatile("s_waitcnt lgkmcnt(0)" ::: "memory");
    __builtin_amdgcn_sched_barrier(0);
    __builtin_amdgcn_s_barrier();
  }
#undef STAGE

  // epilogue: Y = acc + s(t)*bias
#pragma unroll
  for (int mi = 0; mi < 8; ++mi) {
    const int rowb = m0 + wm * 128 + mi * 16;
    const int t = rowb >> 5;   // uniform per 16-row frag
    const float s = (1.0f - __expf(-(float)(t + 1))) * INV_1MA;
#pragma unroll
    for (int ni = 0; ni < 4; ++ni) {
      const int col = n0 + wn * 64 + ni * 16 + r;
      const float sb = s * bias[col];
#pragma unroll
      for (int j = 0; j < 4; ++j)
        Y[(size_t)(rowb + q * 4 + j) * DOUT + col] = acc[mi][ni][j] + sb;
    }
  }
}

// ===========================================================================
// FALLBACK PATH (fp32 GEMM + scan; used only if ws < 64.5 MB)
// ===========================================================================
__launch_bounds__(256, 2)
__global__ void gemm_bias_kernel(const float* __restrict__ X,
                                 const float* __restrict__ W,
                                 const float* __restrict__ bias,
                                 float* __restrict__ Y,
                                 float* __restrict__ halo,
                                 int halo_on)
{
  __shared__ __align__(16) uint16_t As[128 * 64];
  __shared__ __align__(16) uint16_t Bsh[128 * 64];

  const int tid  = threadIdx.x;
  const int lane = tid & 63;
  const int wave = tid >> 6;
  const int wm   = wave >> 1;
  const int wn   = wave & 1;
  const int r    = lane & 15;
  const int q    = lane >> 4;

  const int m0 = blockIdx.y * 128;
  const int n0 = blockIdx.x * 128;

  floatx4 acc[4][4];
#pragma unroll
  for (int i = 0; i < 4; ++i)
#pragma unroll
    for (int j = 0; j < 4; ++j) {
      floatx4 z = {0.0f, 0.0f, 0.0f, 0.0f};
      acc[i][j] = z;
    }

  for (int kt = 0; kt < DIN / 64; ++kt) {
    const int k0 = kt * 64;
#pragma unroll
    for (int j = 0; j < 4; ++j) {
      const int cid = tid + j * 256;
      const int row = cid >> 3;
      const int c   = cid & 7;
      const int slot = (c ^ (row & 7)) << 3;

      const float* ga = &X[(size_t)(m0 + row) * DIN + k0 + c * 8];
      float4 a0 = *(const float4*)ga;
      float4 a1 = *(const float4*)(ga + 4);
      uint4 pa;
      pa.x = pk2(a0.x, a0.y); pa.y = pk2(a0.z, a0.w);
      pa.z = pk2(a1.x, a1.y); pa.w = pk2(a1.z, a1.w);
      *(uint4*)&As[row * 64 + slot] = pa;

      const float* gb = &W[(size_t)(n0 + row) * DIN + k0 + c * 8];
      float4 b0 = *(const float4*)gb;
      float4 b1 = *(const float4*)(gb + 4);
      uint4 pb;
      pb.x = pk2(b0.x, b0.y); pb.y = pk2(b0.z, b0.w);
      pb.z = pk2(b1.x, b1.y); pb.w = pk2(b1.z, b1.w);
      *(uint4*)&Bsh[row * 64 + slot] = pb;
    }
    __syncthreads();

#pragma unroll
    for (int kk = 0; kk < 2; ++kk) {
      bf16x8 af[4], bfr[4];
#pragma unroll
      for (int mi = 0; mi < 4; ++mi) {
        const int row = wm * 64 + mi * 16 + r;
        const int c   = (kk * 4 + q) ^ (row & 7);
        af[mi] = *(const bf16x8*)&As[row * 64 + (c << 3)];
      }
#pragma unroll
      for (int ni = 0; ni < 4; ++ni) {
        const int row = wn * 64 + ni * 16 + r;
        const int c   = (kk * 4 + q) ^ (row & 7);
        bfr[ni] = *(const bf16x8*)&Bsh[row * 64 + (c << 3)];
      }
#pragma unroll
      for (int mi = 0; mi < 4; ++mi)
#pragma unroll
        for (int ni = 0; ni < 4; ++ni)
          acc[mi][ni] = __builtin_amdgcn_mfma_f32_16x16x32_bf16(
              af[mi], bfr[ni], acc[mi][ni], 0, 0, 0);
    }
    __syncthreads();
  }

#pragma unroll
  for (int ni = 0; ni < 4; ++ni) {
    const int col = n0 + wn * 64 + ni * 16 + r;
    const float bv = bias[col];
#pragma unroll
    for (int mi = 0; mi < 4; ++mi) {
      const int rowm = m0 + wm * 64 + mi * 16 + q * 4;
      const int t = rowm >> 5;
      const int b = rowm & 31;
      const int tloc = t & (FCHUNK_T - 1);
      const bool hw = halo_on && (tloc >= FCHUNK_T - FHALO) && (t < T_DIM - FCHUNK_T);
      const size_t hbase = hw
          ? ((size_t)(((t >> 6) + 1) * FHALO + (tloc - (FCHUNK_T - FHALO))) * COLS)
          : 0;
#pragma unroll
      for (int j = 0; j < 4; ++j) {
        const float v = acc[mi][ni][j] + bv;
        Y[(size_t)(rowm + j) * DOUT + col] = v;
        if (hw) halo[hbase + (size_t)(b + j) * DOUT + col] = v;
      }
    }
  }
}

__global__ void scan_kernel(float* __restrict__ Y,
                            const float* __restrict__ halo,
                            int chunk_len)
{
  const int col4 = blockIdx.x * blockDim.x + threadIdx.x;
  const int c = blockIdx.y;

  float4* Y4 = (float4*)Y;
  const float4* H4 = (const float4*)halo;

  float4 carry = {0.0f, 0.0f, 0.0f, 0.0f};
  if (c > 0) {
#pragma unroll
    for (int h = 0; h < FHALO; ++h) {
      float4 v = H4[(size_t)(c * FHALO + h) * COLS4 + col4];
      fma4(carry, v);
    }
  }

  size_t idx = (size_t)c * chunk_len * COLS4 + col4;
  float4 ynext = Y4[idx];
  for (int t = 0; t < chunk_len; ++t) {
    float4 y = ynext;
    if (t + 1 < chunk_len) ynext = Y4[idx + COLS4];
    fma4(carry, y);
    Y4[idx] = carry;
    idx += COLS4;
  }
}

// ---------------------------------------------------------------------------
extern "C" void kernel_launch(void* const* d_in, const int* in_sizes, int n_in,
                              void* d_out, int out_size, void* d_ws, size_t ws_size,
                              hipStream_t stream)
{
  const float* X    = (const float*)d_in[0];  // [T, B, DIN]
  const float* W    = (const float*)d_in[1];  // [DOUT, DIN]
  const float* bias = (const float*)d_in[2];  // [DOUT]
  float* Y = (float*)d_out;                   // [T, B, DOUT]

  const size_t need_new = (size_t)M_DIM * DIN * 2 + (size_t)DOUT * DIN * 2; // 64.5 MiB

  if (ws_size >= need_new) {
    uint16_t* XF = (uint16_t*)d_ws;
    uint16_t* WB = XF + (size_t)M_DIM * DIN;

    dim3 gf(FT_CT, FT_TT + 1);   // (128, 65); y==64 converts W
    filter_x_kernel<<<gf, 256, 0, stream>>>(X, XF, W, WB);
    gemm_bf16_deep<<<512, 512, 0, stream>>>(XF, WB, bias, Y);
  } else {
    float* halo = (float*)d_ws;
    const size_t halo_need = (size_t)FCHUNKS * FHALO * COLS * sizeof(float);
    const int halo_on = (ws_size >= halo_need) ? 1 : 0;

    dim3 g1(DOUT / 128, M_DIM / 128);
    gemm_bias_kernel<<<g1, 256, 0, stream>>>(X, W, bias, Y, halo, halo_on);

    const int n_chunks = halo_on ? FCHUNKS : 1;
    dim3 g2(COLS4 / 256, n_chunks);
    scan_kernel<<<g2, 256, 0, stream>>>(Y, halo, T_DIM / n_chunks);
  }
}

// Round 15
// 86.465 us; speedup vs baseline: 1.2122x; 1.2122x over previous
//
#include <hip/hip_runtime.h>
#include <stdint.h>

// Problem constants
#define T_DIM 2048
#define B_DIM 32
#define DIN   512
#define DOUT  512
#define M_DIM (T_DIM * B_DIM)   // 65536
#define COLS  (B_DIM * DIN)     // 16384
#define COLS4 (COLS / 4)        // 4096

#define ALPHA_F 0.36787944117144233f  // exp(-1)
#define INV_1MA 1.5819767068693265f   // 1/(1-alpha)

// LDS-staged filter tiling (round-11, best measured): per block 64 output t
// x 32 float4 cols, 8-t halo. 72 staged rows x 512B = 36 KB LDS -> 4 blk/CU.
#define FT_T    64
#define FT_HALO 8
#define FT_ROWS (FT_T + FT_HALO)   // 72 staged rows
#define FT_C4   32                 // float4 columns per block (512B/row)
#define FT_TT   (T_DIM / FT_T)     // 32 t-tiles
#define FT_CT   (COLS4 / FT_C4)    // 128 col-tiles

// Fallback-path chunking (fp32 path, only if ws < 64.5 MB)
#define FCHUNKS  32
#define FCHUNK_T 64
#define FHALO    16

typedef float  floatx4 __attribute__((ext_vector_type(4)));
typedef __bf16 bf16x8  __attribute__((ext_vector_type(8)));

// pack two fp32 -> two bf16 (RNE) in one u32
__device__ __forceinline__ uint32_t pk2(float a, float b) {
  uint32_t ua = __float_as_uint(a); ua += 0x7fffu + ((ua >> 16) & 1u);
  uint32_t ub = __float_as_uint(b); ub += 0x7fffu + ((ub >> 16) & 1u);
  return (ua >> 16) | (ub & 0xffff0000u);
}

__device__ __forceinline__ void gload_lds16(const void* g, void* lds) {
  __builtin_amdgcn_global_load_lds(
      (const __attribute__((address_space(1))) void*)g,
      (__attribute__((address_space(3))) void*)lds,
      16, 0, 0);
}

__device__ __forceinline__ void fma4(float4& c, const float4& v) {
  c.x = fmaf(ALPHA_F, c.x, v.x);
  c.y = fmaf(ALPHA_F, c.y, v.y);
  c.z = fmaf(ALPHA_F, c.z, v.z);
  c.w = fmaf(ALPHA_F, c.w, v.w);
}

// ---------------------------------------------------------------------------
// Kernel 1: LDS-staged exponential filter (fp32 X -> bf16 XF) + W conversion.
// grid (FT_CT, FT_TT+1) x 256. blockIdx.y == FT_TT converts W (2048 fl/blk).
// Tile: rows t0-8..t0+63 x 32 float4 (36 KB LDS). Each global_load_lds16
// spans TWO global rows (per-lane global addr: lanes 0-31 row r, 32-63 row
// r+1; LDS dest contiguous 1024B). Halo re-read 12.5%.
// Compute: wave covers 16 out-t as two 8-t segments (seg=lane>>5, col=lane&31)
// each running an 8-halo + 8-out alpha-chain from LDS. >=9 taps everywhere:
// truncation ~2e-4 on xf -> ~7e-5 on out, invisible under bf16 floor 0.0156.
// ---------------------------------------------------------------------------
__global__ void filter_x_kernel(const float* __restrict__ X,
                                uint16_t* __restrict__ XF,
                                const float* __restrict__ W,
                                uint16_t* __restrict__ WB)
{
  __shared__ __align__(16) float4 L4[FT_ROWS * FT_C4];   // 36 KB

  if (blockIdx.y == FT_TT) {
    // ---- W fp32 -> bf16: 128 blocks x 256 thr x 8 floats = 262144 ----
    const int base = (blockIdx.x * 256 + threadIdx.x) * 8;
    const float4* W4 = (const float4*)W;
    float4 w0 = W4[base / 4];
    float4 w1 = W4[base / 4 + 1];
    uint4 p;
    p.x = pk2(w0.x, w0.y); p.y = pk2(w0.z, w0.w);
    p.z = pk2(w1.x, w1.y); p.w = pk2(w1.z, w1.w);
    *(uint4*)&WB[base] = p;
    return;
  }

  const int ct = blockIdx.x;          // col-tile
  const int tt = blockIdx.y;          // t-tile
  const int tid  = threadIdx.x;
  const int lane = tid & 63;
  const int w    = tid >> 6;
  const int t0   = tt * FT_T;
  const size_t gc4 = (size_t)ct * FT_C4;   // base col in float4 units

  const int lrow = lane >> 5;         // 0/1: which of the 2 rows this lane loads
  const int lcol = lane & 31;

  // ---- stage: rows r=0..71 hold t = t0-8+r; 2 rows per instruction ----
  if (tt == 0) {
    // zero halo rows 0..7 (t<0): 8 rows x 512B = 4KB = 256 thr x 16B
    const float4 z = {0.0f, 0.0f, 0.0f, 0.0f};
    L4[tid] = z;
    // rows 8..71 -> t = 0..63: 32 instrs, 8 per wave
#pragma unroll
    for (int i = 0; i < 8; ++i) {
      const int row = 8 + (w * 8 + i) * 2;       // 8,10,..,70
      gload_lds16(X + ((size_t)(t0 + row - 8 + lrow) * COLS4 + gc4 + lcol) * 4,
                  &L4[row * FT_C4]);
    }
  } else {
    // rows 0..71: 36 instrs, 9 per wave
#pragma unroll
    for (int i = 0; i < 9; ++i) {
      const int row = (w * 9 + i) * 2;           // 0,2,..,70
      gload_lds16(X + ((size_t)(t0 - 8 + row + lrow) * COLS4 + gc4 + lcol) * 4,
                  &L4[row * FT_C4]);
    }
  }
  __syncthreads();

  // ---- compute: wave w covers out-t [w*16, w*16+16) as 2 segments ----
  const int seg = lane >> 5;          // 0/1: 8-t segment within the wave
  const int col = lane & 31;
  const int rbase = w * 16 + seg * 8; // first staged row of the chain (halo)
  float4 carry = {0.0f, 0.0f, 0.0f, 0.0f};
#pragma unroll
  for (int j = 0; j < 16; ++j) {
    float4 v = L4[(rbase + j) * FT_C4 + col];
    fma4(carry, v);
    if (j >= 8) {
      const int o = rbase + j - 8;    // local output t (0..63)
      uint2 p;
      p.x = pk2(carry.x, carry.y);
      p.y = pk2(carry.z, carry.w);
      *(uint2*)&XF[((size_t)(t0 + o) * COLS4 + gc4 + col) * 4] = p;
    }
  }
}

// ---------------------------------------------------------------------------
// Kernel 2: bf16 GEMM (m97 structure): Y[m,n] = XF[m,:]·WB[n,:] + s(t)·bias[n]
// BM=BN=128, BK=64; 256 thr / 4 waves (2x2), 64x64 per wave.
// global_load_lds width16 with PRE-SWIZZLED global source (linear LDS dest),
// XOR-swizzled ds_read_b128 (conflict-free), chunked XCD swizzle.
// Measured at ~905 TF = the m97-structure ceiling for this shape.
// ---------------------------------------------------------------------------
__launch_bounds__(256, 4)
__global__ void gemm_bf16_kernel(const uint16_t* __restrict__ XF,
                                 const uint16_t* __restrict__ WB,
                                 const float* __restrict__ bias,
                                 float* __restrict__ Y)
{
  __shared__ __align__(16) uint16_t As[128 * 64];
  __shared__ __align__(16) uint16_t Bs[128 * 64];

  const int bid = blockIdx.x;
  const int lg = (bid & 7) * 256 + (bid >> 3);
  const int n0 = (lg & 3) * 128;
  const int m0 = (lg >> 2) * 128;

  const int tid  = threadIdx.x;
  const int lane = tid & 63;
  const int w    = tid >> 6;
  const int r    = lane & 15;
  const int q    = lane >> 4;
  const int wm   = w >> 1;
  const int wn   = w & 1;

  const int srow_base = w * 32 + (lane >> 3);
  const int schunk    = lane & 7;

  floatx4 acc[4][4];
#pragma unroll
  for (int i = 0; i < 4; ++i)
#pragma unroll
    for (int j = 0; j < 4; ++j) {
      floatx4 z = {0.0f, 0.0f, 0.0f, 0.0f};
      acc[i][j] = z;
    }

  for (int kt = 0; kt < DIN / 64; ++kt) {
    const int k0 = kt * 64;
#pragma unroll
    for (int i = 0; i < 4; ++i) {
      const int row = srow_base + i * 8;
      const int sc = schunk ^ (row & 7);
      gload_lds16(XF + (size_t)(m0 + row) * DIN + k0 + sc * 8,
                  &As[(w * 32 + i * 8) * 64]);
      gload_lds16(WB + (size_t)(n0 + row) * DIN + k0 + sc * 8,
                  &Bs[(w * 32 + i * 8) * 64]);
    }
    __syncthreads();

#pragma unroll
    for (int kk = 0; kk < 2; ++kk) {
      bf16x8 af[4], bfr[4];
#pragma unroll
      for (int mi = 0; mi < 4; ++mi) {
        const int row = wm * 64 + mi * 16 + r;
        const int cch = (kk * 4 + q) ^ (row & 7);
        af[mi] = *(const bf16x8*)&As[row * 64 + (cch << 3)];
      }
#pragma unroll
      for (int ni = 0; ni < 4; ++ni) {
        const int row = wn * 64 + ni * 16 + r;
        const int cch = (kk * 4 + q) ^ (row & 7);
        bfr[ni] = *(const bf16x8*)&Bs[row * 64 + (cch << 3)];
      }
#pragma unroll
      for (int mi = 0; mi < 4; ++mi)
#pragma unroll
        for (int ni = 0; ni < 4; ++ni)
          acc[mi][ni] = __builtin_amdgcn_mfma_f32_16x16x32_bf16(
              af[mi], bfr[ni], acc[mi][ni], 0, 0, 0);
    }
    __syncthreads();
  }

#pragma unroll
  for (int mi = 0; mi < 4; ++mi) {
    const int rowb = m0 + wm * 64 + mi * 16;
    const int t = rowb >> 5;
    const float s = (1.0f - __expf(-(float)(t + 1))) * INV_1MA;
#pragma unroll
    for (int ni = 0; ni < 4; ++ni) {
      const int col = n0 + wn * 64 + ni * 16 + r;
      const float sb = s * bias[col];
#pragma unroll
      for (int j = 0; j < 4; ++j)
        Y[(size_t)(rowb + q * 4 + j) * DOUT + col] = acc[mi][ni][j] + sb;
    }
  }
}

// ===========================================================================
// FALLBACK PATH (fp32 GEMM + scan; used only if ws < 64.5 MB)
// ===========================================================================
__launch_bounds__(256, 2)
__global__ void gemm_bias_kernel(const float* __restrict__ X,
                                 const float* __restrict__ W,
                                 const float* __restrict__ bias,
                                 float* __restrict__ Y,
                                 float* __restrict__ halo,
                                 int halo_on)
{
  __shared__ __align__(16) uint16_t As[128 * 64];
  __shared__ __align__(16) uint16_t Bsh[128 * 64];

  const int tid  = threadIdx.x;
  const int lane = tid & 63;
  const int wave = tid >> 6;
  const int wm   = wave >> 1;
  const int wn   = wave & 1;
  const int r    = lane & 15;
  const int q    = lane >> 4;

  const int m0 = blockIdx.y * 128;
  const int n0 = blockIdx.x * 128;

  floatx4 acc[4][4];
#pragma unroll
  for (int i = 0; i < 4; ++i)
#pragma unroll
    for (int j = 0; j < 4; ++j) {
      floatx4 z = {0.0f, 0.0f, 0.0f, 0.0f};
      acc[i][j] = z;
    }

  for (int kt = 0; kt < DIN / 64; ++kt) {
    const int k0 = kt * 64;
#pragma unroll
    for (int j = 0; j < 4; ++j) {
      const int cid = tid + j * 256;
      const int row = cid >> 3;
      const int c   = cid & 7;
      const int slot = (c ^ (row & 7)) << 3;

      const float* ga = &X[(size_t)(m0 + row) * DIN + k0 + c * 8];
      float4 a0 = *(const float4*)ga;
      float4 a1 = *(const float4*)(ga + 4);
      uint4 pa;
      pa.x = pk2(a0.x, a0.y); pa.y = pk2(a0.z, a0.w);
      pa.z = pk2(a1.x, a1.y); pa.w = pk2(a1.z, a1.w);
      *(uint4*)&As[row * 64 + slot] = pa;

      const float* gb = &W[(size_t)(n0 + row) * DIN + k0 + c * 8];
      float4 b0 = *(const float4*)gb;
      float4 b1 = *(const float4*)(gb + 4);
      uint4 pb;
      pb.x = pk2(b0.x, b0.y); pb.y = pk2(b0.z, b0.w);
      pb.z = pk2(b1.x, b1.y); pb.w = pk2(b1.z, b1.w);
      *(uint4*)&Bsh[row * 64 + slot] = pb;
    }
    __syncthreads();

#pragma unroll
    for (int kk = 0; kk < 2; ++kk) {
      bf16x8 af[4], bfr[4];
#pragma unroll
      for (int mi = 0; mi < 4; ++mi) {
        const int row = wm * 64 + mi * 16 + r;
        const int c   = (kk * 4 + q) ^ (row & 7);
        af[mi] = *(const bf16x8*)&As[row * 64 + (c << 3)];
      }
#pragma unroll
      for (int ni = 0; ni < 4; ++ni) {
        const int row = wn * 64 + ni * 16 + r;
        const int c   = (kk * 4 + q) ^ (row & 7);
        bfr[ni] = *(const bf16x8*)&Bsh[row * 64 + (c << 3)];
      }
#pragma unroll
      for (int mi = 0; mi < 4; ++mi)
#pragma unroll
        for (int ni = 0; ni < 4; ++ni)
          acc[mi][ni] = __builtin_amdgcn_mfma_f32_16x16x32_bf16(
              af[mi], bfr[ni], acc[mi][ni], 0, 0, 0);
    }
    __syncthreads();
  }

#pragma unroll
  for (int ni = 0; ni < 4; ++ni) {
    const int col = n0 + wn * 64 + ni * 16 + r;
    const float bv = bias[col];
#pragma unroll
    for (int mi = 0; mi < 4; ++mi) {
      const int rowm = m0 + wm * 64 + mi * 16 + q * 4;
      const int t = rowm >> 5;
      const int b = rowm & 31;
      const int tloc = t & (FCHUNK_T - 1);
      const bool hw = halo_on && (tloc >= FCHUNK_T - FHALO) && (t < T_DIM - FCHUNK_T);
      const size_t hbase = hw
          ? ((size_t)(((t >> 6) + 1) * FHALO + (tloc - (FCHUNK_T - FHALO))) * COLS)
          : 0;
#pragma unroll
      for (int j = 0; j < 4; ++j) {
        const float v = acc[mi][ni][j] + bv;
        Y[(size_t)(rowm + j) * DOUT + col] = v;
        if (hw) halo[hbase + (size_t)(b + j) * DOUT + col] = v;
      }
    }
  }
}

__global__ void scan_kernel(float* __restrict__ Y,
                            const float* __restrict__ halo,
                            int chunk_len)
{
  const int col4 = blockIdx.x * blockDim.x + threadIdx.x;
  const int c = blockIdx.y;

  float4* Y4 = (float4*)Y;
  const float4* H4 = (const float4*)halo;

  float4 carry = {0.0f, 0.0f, 0.0f, 0.0f};
  if (c > 0) {
#pragma unroll
    for (int h = 0; h < FHALO; ++h) {
      float4 v = H4[(size_t)(c * FHALO + h) * COLS4 + col4];
      fma4(carry, v);
    }
  }

  size_t idx = (size_t)c * chunk_len * COLS4 + col4;
  float4 ynext = Y4[idx];
  for (int t = 0; t < chunk_len; ++t) {
    float4 y = ynext;
    if (t + 1 < chunk_len) ynext = Y4[idx + COLS4];
    fma4(carry, y);
    Y4[idx] = carry;
    idx += COLS4;
  }
}

// ---------------------------------------------------------------------------
extern "C" void kernel_launch(void* const* d_in, const int* in_sizes, int n_in,
                              void* d_out, int out_size, void* d_ws, size_t ws_size,
                              hipStream_t stream)
{
  const float* X    = (const float*)d_in[0];  // [T, B, DIN]
  const float* W    = (const float*)d_in[1];  // [DOUT, DIN]
  const float* bias = (const float*)d_in[2];  // [DOUT]
  float* Y = (float*)d_out;                   // [T, B, DOUT]

  const size_t need_new = (size_t)M_DIM * DIN * 2 + (size_t)DOUT * DIN * 2; // 64.5 MiB

  if (ws_size >= need_new) {
    uint16_t* XF = (uint16_t*)d_ws;
    uint16_t* WB = XF + (size_t)M_DIM * DIN;

    dim3 gf(FT_CT, FT_TT + 1);   // (128, 33); y==32 converts W
    filter_x_kernel<<<gf, 256, 0, stream>>>(X, XF, W, WB);
    gemm_bf16_kernel<<<2048, 256, 0, stream>>>(XF, WB, bias, Y);
  } else {
    float* halo = (float*)d_ws;
    const size_t halo_need = (size_t)FCHUNKS * FHALO * COLS * sizeof(float);
    const int halo_on = (ws_size >= halo_need) ? 1 : 0;

    dim3 g1(DOUT / 128, M_DIM / 128);
    gemm_bias_kernel<<<g1, 256, 0, stream>>>(X, W, bias, Y, halo, halo_on);

    const int n_chunks = halo_on ? FCHUNKS : 1;
    dim3 g2(COLS4 / 256, n_chunks);
    scan_kernel<<<g2, 256, 0, stream>>>(Y, halo, T_DIM / n_chunks);
  }
}